// Round 2
// baseline (4703.804 us; speedup 1.0000x reference)
//
#include <hip/hip_runtime.h>

// DepthFlowProjection (DAIN, fillhole=0) forward.
// flow:  [B,2,H,W] f32, depth: [B,1,H,W] f32  -> out: [B,2,H,W] f32
//
// Round-2 layout: interleaved accumulator cells {cnt, sx, sy, pad} (16B,
// aligned) in d_ws so the 3 atomics per corner hit ONE 32B sector, and the
// L/R corner pair hits one 64B line. Goal: fewer L2->fabric atomic
// transactions (the round-1 bottleneck: 2.73 GB WRITE_SIZE, 25 G atomics/s).

__global__ void dfp_scatter_cells(const float* __restrict__ flow,
                                  const float* __restrict__ depth,
                                  float4* __restrict__ cells,  // [B*H*W] {cnt,sx,sy,pad}
                                  int B, int H, int W) {
    const int HWl = H * W;
    const long total = (long)B * HWl;
    long idx = (long)blockIdx.x * blockDim.x + threadIdx.x;
    if (idx >= total) return;

    int b = (int)(idx / HWl);
    int p = (int)(idx - (long)b * HWl);
    int y = p / W;
    int x = p - y * W;

    const float* f = flow + (size_t)b * 2 * HWl;
    float fx = f[p];
    float fy = f[HWl + p];
    float d  = depth[idx];

    float x2 = (float)x + fx;
    float y2 = (float)y + fy;

    if (!(x2 >= 0.0f && y2 >= 0.0f && x2 <= (float)(W - 1) && y2 <= (float)(H - 1)))
        return;

    int ixL = (int)floorf(x2);
    int iyT = (int)floorf(y2);
    ixL = min(max(ixL, 0), W - 1);
    iyT = min(max(iyT, 0), H - 1);
    int ixR = min(ixL + 1, W - 1);
    int iyB = min(iyT + 1, H - 1);

    float vx = -fx * d;
    float vy = -fy * d;

    float* base = (float*)(cells + (size_t)b * HWl);

    int c00 = (iyT * W + ixL) * 4;
    int c01 = (iyT * W + ixR) * 4;
    int c10 = (iyB * W + ixL) * 4;
    int c11 = (iyB * W + ixR) * 4;

    // per corner: 3 atomics into one 16B-aligned cell (single 32B sector)
    atomicAdd(base + c00 + 0, d);
    atomicAdd(base + c00 + 1, vx);
    atomicAdd(base + c00 + 2, vy);

    atomicAdd(base + c01 + 0, d);
    atomicAdd(base + c01 + 1, vx);
    atomicAdd(base + c01 + 2, vy);

    atomicAdd(base + c10 + 0, d);
    atomicAdd(base + c10 + 1, vx);
    atomicAdd(base + c10 + 2, vy);

    atomicAdd(base + c11 + 0, d);
    atomicAdd(base + c11 + 1, vx);
    atomicAdd(base + c11 + 2, vy);
}

__global__ void dfp_normalize_cells(const float4* __restrict__ cells,
                                    float* __restrict__ out,
                                    int B, int HWl) {
    const long total = (long)B * HWl;
    long idx = (long)blockIdx.x * blockDim.x + threadIdx.x;
    if (idx >= total) return;

    int b = (int)(idx / HWl);
    int p = (int)(idx - (long)b * HWl);

    float4 c = cells[idx];
    float denom = (c.x > 0.0f) ? c.x : 1.0f;

    size_t o = (size_t)b * 2 * HWl + p;
    out[o]       = c.y / denom;
    out[o + HWl] = c.z / denom;
}

// ---------------- fallback (round-1) path: 3 separate planes ----------------

__global__ void dfp_scatter(const float* __restrict__ flow,
                            const float* __restrict__ depth,
                            float* __restrict__ out,
                            float* __restrict__ count,
                            int B, int H, int W) {
    const int HWl = H * W;
    const long total = (long)B * HWl;
    long idx = (long)blockIdx.x * blockDim.x + threadIdx.x;
    if (idx >= total) return;

    int b = (int)(idx / HWl);
    int p = (int)(idx - (long)b * HWl);
    int y = p / W;
    int x = p - y * W;

    const float* f = flow + (size_t)b * 2 * HWl;
    float fx = f[p];
    float fy = f[HWl + p];
    float d  = depth[idx];

    float x2 = (float)x + fx;
    float y2 = (float)y + fy;
    if (!(x2 >= 0.0f && y2 >= 0.0f && x2 <= (float)(W - 1) && y2 <= (float)(H - 1)))
        return;

    int ixL = min(max((int)floorf(x2), 0), W - 1);
    int iyT = min(max((int)floorf(y2), 0), H - 1);
    int ixR = min(ixL + 1, W - 1);
    int iyB = min(iyT + 1, H - 1);

    float vx = -fx * d;
    float vy = -fy * d;

    float* cnt_b  = count + (size_t)b * HWl;
    float* outx_b = out + (size_t)b * 2 * HWl;
    float* outy_b = outx_b + HWl;

    int o00 = iyT * W + ixL, o01 = iyT * W + ixR;
    int o10 = iyB * W + ixL, o11 = iyB * W + ixR;

    atomicAdd(&cnt_b[o00], d);  atomicAdd(&cnt_b[o01], d);
    atomicAdd(&cnt_b[o10], d);  atomicAdd(&cnt_b[o11], d);
    atomicAdd(&outx_b[o00], vx); atomicAdd(&outx_b[o01], vx);
    atomicAdd(&outx_b[o10], vx); atomicAdd(&outx_b[o11], vx);
    atomicAdd(&outy_b[o00], vy); atomicAdd(&outy_b[o01], vy);
    atomicAdd(&outy_b[o10], vy); atomicAdd(&outy_b[o11], vy);
}

__global__ void dfp_normalize(float* __restrict__ out,
                              const float* __restrict__ count,
                              int B, int HWl) {
    const long total = (long)B * HWl;
    long idx = (long)blockIdx.x * blockDim.x + threadIdx.x;
    if (idx >= total) return;

    int b = (int)(idx / HWl);
    int p = (int)(idx - (long)b * HWl);

    float c = count[idx];
    float denom = (c > 0.0f) ? c : 1.0f;

    size_t o = (size_t)b * 2 * HWl + p;
    out[o]       = out[o] / denom;
    out[o + HWl] = out[o + HWl] / denom;
}

extern "C" void kernel_launch(void* const* d_in, const int* in_sizes, int n_in,
                              void* d_out, int out_size, void* d_ws, size_t ws_size,
                              hipStream_t stream) {
    const float* flow  = (const float*)d_in[0];
    const float* depth = (const float*)d_in[1];
    float* out = (float*)d_out;

    const int H = 1080, W = 1920;
    const int HWl = H * W;
    const int B = in_sizes[1] / HWl;
    const long total = (long)B * HWl;

    const int threads = 256;
    const int blocks = (int)((total + threads - 1) / threads);

    const size_t cells_bytes = (size_t)total * 4 * sizeof(float);

    if (ws_size >= cells_bytes) {
        float4* cells = (float4*)d_ws;
        hipMemsetAsync(d_ws, 0, cells_bytes, stream);
        dfp_scatter_cells<<<blocks, threads, 0, stream>>>(flow, depth, cells, B, H, W);
        dfp_normalize_cells<<<blocks, threads, 0, stream>>>(cells, out, B, HWl);
    } else {
        float* cnt = (float*)d_ws;
        hipMemsetAsync(d_out, 0, (size_t)total * 2 * sizeof(float), stream);
        hipMemsetAsync(d_ws, 0, (size_t)total * sizeof(float), stream);
        dfp_scatter<<<blocks, threads, 0, stream>>>(flow, depth, out, cnt, B, H, W);
        dfp_normalize<<<blocks, threads, 0, stream>>>(out, cnt, B, HWl);
    }
}

// Round 4
// 656.851 us; speedup vs baseline: 7.1611x; 7.1611x over previous
//
#include <hip/hip_runtime.h>

// DepthFlowProjection (DAIN, fillhole=0) forward — LDS-privatized scatter,
// race-free two-kernel version.
//
// flow:  [B,2,H,W] f32, depth: [B,1,H,W] f32  -> out: [B,2,H,W] f32
//
// Round-1/2: device f32 atomics are the bottleneck (~25 G/s, no merging).
// Round-3 bug: leak cells were read by corner-owning tiles' flush while other
// blocks were still writing them -> cross-block race. Fix: kernel 1 writes
// RAW tile sums (non-atomic, exclusive ownership) + leak atomics; kernel 2
// (stream-ordered after) combines tile + leak and normalizes.

constexpr int W  = 1920, H = 1080;
constexpr int HW = W * H;
constexpr int Sh = 40, Wt = 160, R = 24;
constexpr int TX = W / Wt, TY = H / Sh;     // 12, 27
constexpr int SW = Sh * Wt;                 // 6400 px per tile
constexpr float LEAK_THR = (float)(R - 1);  // 23.0f

// Kernel 1: per-tile LDS scatter. Writes raw sx/sy to out (non-atomic,
// exclusive), raw cnt to cnt_out[(b*HW+gp)*cnt_stride], and big-flow pixel
// contributions via global atomics into leak cells {cnt,sx,sy,(pad/cnt_tile)}.
__global__ __launch_bounds__(512) void dfp_tile(
    const float* __restrict__ flow, const float* __restrict__ depth,
    float* __restrict__ leak,      // [B*HW] float4 cells, zeroed before launch
    float* __restrict__ cnt_out,   // raw tile cnt, stride cnt_stride
    int cnt_stride,
    float* __restrict__ out, int B)
{
    __shared__ __align__(16) float acc[3 * SW];   // planes: cnt, sx, sy (76.8 KB)
    const int tid = threadIdx.x;

    int blk = blockIdx.x;
    int b   = blk / (TX * TY);
    int t   = blk - b * (TX * TY);
    int ty  = t / TX;
    int tx  = t - ty * TX;
    const int Y0 = ty * Sh, X0 = tx * Wt;

    float4* accv = (float4*)acc;
    for (int i = tid; i < 3 * SW / 4; i += 512) accv[i] = make_float4(0.f, 0.f, 0.f, 0.f);
    __syncthreads();

    const float* fxp = flow + (size_t)b * 2 * HW;
    const float* fyp = fxp + HW;
    const float* dp  = depth + (size_t)b * HW;

    const int r0 = max(Y0 - R, 0), r1 = min(Y0 + Sh + R, H);
    const int c0 = max(X0 - R, 0), c1 = min(X0 + Wt + R, W);

    for (int r = r0 + (tid >> 6); r < r1; r += 8) {
        for (int c = c0 + (tid & 63); c < c1; c += 64) {
            int p = r * W + c;
            float fx = fxp[p], fy = fyp[p];
            float x2 = (float)c + fx, y2 = (float)r + fy;
            if (!(x2 >= 0.f && y2 >= 0.f && x2 <= (float)(W - 1) && y2 <= (float)(H - 1)))
                continue;
            float d = dp[p];
            int ixL = (int)floorf(x2), iyT = (int)floorf(y2);
            ixL = min(max(ixL, 0), W - 1);
            iyT = min(max(iyT, 0), H - 1);
            int ixR = min(ixL + 1, W - 1), iyB = min(iyT + 1, H - 1);
            float vx = -fx * d, vy = -fy * d;

            if (fabsf(fx) <= LEAK_THR && fabsf(fy) <= LEAK_THR) {
                // corner offsets from (r,c) are in [-23,+24] ⊆ halo R=24:
                // every corner's owning tile reads (r,c) -> add owned corners.
#define CORNER(iy, ix) do {                                              \
    if ((iy) >= Y0 && (iy) < Y0 + Sh && (ix) >= X0 && (ix) < X0 + Wt) {  \
        int o = ((iy) - Y0) * Wt + ((ix) - X0);                          \
        atomicAdd(&acc[o],          d);                                  \
        atomicAdd(&acc[o + SW],     vx);                                 \
        atomicAdd(&acc[o + 2*SW],   vy);                                 \
    } } while (0)
                CORNER(iyT, ixL); CORNER(iyT, ixR);
                CORNER(iyB, ixL); CORNER(iyB, ixR);
#undef CORNER
            } else if (r >= Y0 && r < Y0 + Sh && c >= X0 && c < X0 + Wt) {
                // rare big-flow pixel: handled once (by its owning tile) via
                // global atomics into leak cells.
                size_t base = (size_t)b * HW * 4;
#define GCORNER(iy, ix) do {                                             \
    size_t o = base + (size_t)((iy) * W + (ix)) * 4;                     \
    atomicAdd(leak + o + 0, d);                                          \
    atomicAdd(leak + o + 1, vx);                                         \
    atomicAdd(leak + o + 2, vy);                                         \
    } while (0)
                GCORNER(iyT, ixL); GCORNER(iyT, ixR);
                GCORNER(iyB, ixL); GCORNER(iyB, ixR);
#undef GCORNER
            }
        }
    }
    __syncthreads();

    // flush RAW sums: each output pixel owned by exactly one block.
    float* outx = out + (size_t)b * 2 * HW;
    float* outy = outx + HW;
    for (int i = tid; i < SW; i += 512) {
        int ly = i / Wt;
        int lx = i - ly * Wt;
        int gp = (Y0 + ly) * W + (X0 + lx);
        outx[gp] = acc[i + SW];
        outy[gp] = acc[i + 2 * SW];
        cnt_out[(size_t)((size_t)b * HW + gp) * cnt_stride] = acc[i];
    }
}

// Kernel 2: combine tile sums + leak, normalize. Runs after kernel 1
// completes (stream order) -> no race.
__global__ void dfp_finalize(const float4* __restrict__ leak,
                             const float* __restrict__ cnt_in,
                             int cnt_stride,
                             float* __restrict__ out, int B)
{
    const long total = (long)B * HW;
    long idx = (long)blockIdx.x * blockDim.x + threadIdx.x;
    if (idx >= total) return;
    int b = (int)(idx / HW);
    int p = (int)(idx - (long)b * HW);

    float4 lk = leak[idx];
    float cnt = cnt_in[(size_t)idx * cnt_stride] + lk.x;
    float den = (cnt > 0.f) ? cnt : 1.f;

    size_t o = (size_t)b * 2 * HW + p;
    out[o]      = (out[o]      + lk.y) / den;
    out[o + HW] = (out[o + HW] + lk.z) / den;
}

// ---------------- fallback (round-1) path if ws is too small ----------------

__global__ void dfp_scatter(const float* __restrict__ flow,
                            const float* __restrict__ depth,
                            float* __restrict__ out,
                            float* __restrict__ count, int B)
{
    const long total = (long)B * HW;
    long idx = (long)blockIdx.x * blockDim.x + threadIdx.x;
    if (idx >= total) return;
    int b = (int)(idx / HW);
    int p = (int)(idx - (long)b * HW);
    int y = p / W;
    int x = p - y * W;
    const float* f = flow + (size_t)b * 2 * HW;
    float fx = f[p], fy = f[HW + p], d = depth[idx];
    float x2 = (float)x + fx, y2 = (float)y + fy;
    if (!(x2 >= 0.f && y2 >= 0.f && x2 <= (float)(W - 1) && y2 <= (float)(H - 1)))
        return;
    int ixL = min(max((int)floorf(x2), 0), W - 1);
    int iyT = min(max((int)floorf(y2), 0), H - 1);
    int ixR = min(ixL + 1, W - 1), iyB = min(iyT + 1, H - 1);
    float vx = -fx * d, vy = -fy * d;
    float* cnt_b  = count + (size_t)b * HW;
    float* outx_b = out + (size_t)b * 2 * HW;
    float* outy_b = outx_b + HW;
    int o00 = iyT * W + ixL, o01 = iyT * W + ixR;
    int o10 = iyB * W + ixL, o11 = iyB * W + ixR;
    atomicAdd(&cnt_b[o00], d);   atomicAdd(&cnt_b[o01], d);
    atomicAdd(&cnt_b[o10], d);   atomicAdd(&cnt_b[o11], d);
    atomicAdd(&outx_b[o00], vx); atomicAdd(&outx_b[o01], vx);
    atomicAdd(&outx_b[o10], vx); atomicAdd(&outx_b[o11], vx);
    atomicAdd(&outy_b[o00], vy); atomicAdd(&outy_b[o01], vy);
    atomicAdd(&outy_b[o11], vy); atomicAdd(&outy_b[o10], vy);
}

__global__ void dfp_normalize(float* __restrict__ out,
                              const float* __restrict__ count, int B)
{
    const long total = (long)B * HW;
    long idx = (long)blockIdx.x * blockDim.x + threadIdx.x;
    if (idx >= total) return;
    int b = (int)(idx / HW);
    int p = (int)(idx - (long)b * HW);
    float c = count[idx];
    float den = (c > 0.f) ? c : 1.f;
    size_t o = (size_t)b * 2 * HW + p;
    out[o]      = out[o] / den;
    out[o + HW] = out[o + HW] / den;
}

extern "C" void kernel_launch(void* const* d_in, const int* in_sizes, int n_in,
                              void* d_out, int out_size, void* d_ws, size_t ws_size,
                              hipStream_t stream) {
    const float* flow  = (const float*)d_in[0];
    const float* depth = (const float*)d_in[1];
    float* out = (float*)d_out;

    const int B = in_sizes[1] / HW;
    const long total = (long)B * HW;

    const size_t cell_bytes  = (size_t)total * 4 * sizeof(float);  // leak cells
    const size_t plane_bytes = (size_t)total * sizeof(float);      // cnt plane

    const int fin_threads = 256;
    const int fin_blocks  = (int)((total + fin_threads - 1) / fin_threads);

    if (ws_size >= cell_bytes + plane_bytes) {
        // clean layout: [leak cells float4][cnt plane]
        float* leak = (float*)d_ws;
        float* cnt  = leak + (size_t)total * 4;
        hipMemsetAsync(d_ws, 0, cell_bytes, stream);  // cnt plane fully written by k1
        dfp_tile<<<B * TX * TY, 512, 0, stream>>>(flow, depth, leak, cnt, 1, out, B);
        dfp_finalize<<<fin_blocks, fin_threads, 0, stream>>>((const float4*)leak, cnt, 1, out, B);
    } else if (ws_size >= cell_bytes) {
        // compact layout: cnt_tile stored in leak cell .w (different dword
        // than the atomically-updated .x/.y/.z -> no same-address conflict)
        float* leak = (float*)d_ws;
        hipMemsetAsync(d_ws, 0, cell_bytes, stream);
        dfp_tile<<<B * TX * TY, 512, 0, stream>>>(flow, depth, leak, leak + 3, 4, out, B);
        dfp_finalize<<<fin_blocks, fin_threads, 0, stream>>>((const float4*)leak, leak + 3, 4, out, B);
    } else {
        // round-1 global-atomics fallback
        const int threads = 256;
        const int blocks = (int)((total + threads - 1) / threads);
        float* cnt = (float*)d_ws;
        hipMemsetAsync(d_out, 0, (size_t)total * 2 * sizeof(float), stream);
        hipMemsetAsync(d_ws, 0, plane_bytes, stream);
        dfp_scatter<<<blocks, threads, 0, stream>>>(flow, depth, out, cnt, B);
        dfp_normalize<<<blocks, threads, 0, stream>>>(out, cnt, B);
    }
}